// Round 2
// baseline (50.105 us; speedup 1.0000x reference)
//
#include <hip/hip_runtime.h>

// Window_Crop: per-batch sliding-window average pooling over 5 aspect ratios
// (stride 1) + argmax over first 4 ratio groups.
//
// Ratios (exact Python float semantics: 1024 // 25.6 == 39.0, not 40!):
//   (32,32) N=6561  off 0
//   (25,39) N=6512  off 6561
//   (39,25) N=6512  off 13073
//   (38,26) N=6525  off 19585
//   (26,38) N=6525  off 26110   (excluded from argmax)
//   total 32635, argmax over [0, 26110)
//
// Algorithm: one block per batch image. Build 113x113 integral image in LDS,
// then every window average = (4 LDS reads) * inv_area. Block-wide argmax
// reduction with first-index tie-break.

#define B_TOTAL   1024
#define HW        112
#define NPIX      (HW * HW)          // 12544
#define PITCH     113                // integral image pitch (row 0 / col 0 = 0)
#define TOTAL_W   32635
#define BLOCK     256

template<int KH, int KW, int OFF, bool TRACK>
__device__ __forceinline__ void windows_group(const float* __restrict__ S,
                                              float* __restrict__ out_scores,
                                              int tid, float& bestv, int& besti) {
    constexpr int OH = HW - KH + 1;
    constexpr int OW = HW - KW + 1;
    constexpr int N  = OH * OW;
    const float inv_area = 1.0f / (float)(KH * KW);
    for (int w = tid; w < N; w += BLOCK) {
        const int i = w / OW;          // compile-time-constant divisor -> magic mul
        const int j = w - i * OW;
        const float s = S[(i + KH) * PITCH + (j + KW)]
                      - S[ i       * PITCH + (j + KW)]
                      - S[(i + KH) * PITCH +  j      ]
                      + S[ i       * PITCH +  j      ];
        const float sc = s * inv_area;
        out_scores[OFF + w] = sc;
        if constexpr (TRACK) {
            if (sc > bestv) { bestv = sc; besti = OFF + w; }
        }
    }
}

__global__ __launch_bounds__(BLOCK)
void window_crop_kernel(const float* __restrict__ x, float* __restrict__ out) {
    __shared__ float S[PITCH * PITCH];     // 51,076 B integral image
    __shared__ float rv[BLOCK];
    __shared__ int   ri[BLOCK];

    const int b   = blockIdx.x;
    const int tid = threadIdx.x;
    const float* img = x + (size_t)b * NPIX;

    // zero row 0 and column 0 of the integral image
    for (int i = tid; i < PITCH; i += BLOCK) {
        S[i] = 0.0f;
        S[i * PITCH] = 0.0f;
    }

    // load image into S[1..112][1..112] (float4 global loads; 112 % 4 == 0)
    const float4* img4 = (const float4*)img;
    for (int i = tid; i < NPIX / 4; i += BLOCK) {
        const int r = i / (HW / 4);                 // row
        const int c = (i - r * (HW / 4)) * 4;       // col (multiple of 4)
        const float4 v = img4[i];
        float* dst = &S[(r + 1) * PITCH + (c + 1)];
        dst[0] = v.x; dst[1] = v.y; dst[2] = v.z; dst[3] = v.w;
    }
    __syncthreads();

    // row-wise inclusive prefix sums (rows 1..112), one thread per row.
    // LDS bank: addresses stride PITCH=113 floats across threads; 113%32=17,
    // gcd(17,32)=1 -> conflict-free.
    if (tid < HW) {
        float run = 0.0f;
        float* row = &S[(tid + 1) * PITCH];
        #pragma unroll 4
        for (int c = 1; c <= HW; ++c) { run += row[c]; row[c] = run; }
    }
    __syncthreads();

    // column-wise prefix sums (cols 1..112), one thread per column.
    // threads access consecutive addresses each step -> conflict-free.
    if (tid < HW) {
        float run = 0.0f;
        const int col = tid + 1;
        #pragma unroll 4
        for (int r = 1; r <= HW; ++r) {
            run += S[r * PITCH + col];
            S[r * PITCH + col] = run;
        }
    }
    __syncthreads();

    // window scores for all 5 ratio groups + argmax over groups 0..3
    float bestv = -3.402823466e+38f;
    int   besti = 0;
    float* out_scores = out + 2 * B_TOTAL + (size_t)b * TOTAL_W;

    windows_group<32, 32,     0, true >(S, out_scores, tid, bestv, besti);
    windows_group<25, 39,  6561, true >(S, out_scores, tid, bestv, besti);
    windows_group<39, 25, 13073, true >(S, out_scores, tid, bestv, besti);
    windows_group<38, 26, 19585, true >(S, out_scores, tid, bestv, besti);
    windows_group<26, 38, 26110, false>(S, out_scores, tid, bestv, besti);

    // block argmax reduction, first-index tie-break (matches jnp.argmax)
    rv[tid] = bestv;
    ri[tid] = besti;
    __syncthreads();
    for (int s = BLOCK / 2; s > 0; s >>= 1) {
        if (tid < s) {
            const float ov = rv[tid + s];
            const int   oi = ri[tid + s];
            if (ov > rv[tid] || (ov == rv[tid] && oi < ri[tid])) {
                rv[tid] = ov; ri[tid] = oi;
            }
        }
        __syncthreads();
    }
    if (tid == 0) {
        out[b]           = (float)ri[0];   // idx (exact in fp32: < 2^24)
        out[B_TOTAL + b] = rv[0];          // prop_scores
    }
}

extern "C" void kernel_launch(void* const* d_in, const int* in_sizes, int n_in,
                              void* d_out, int out_size, void* d_ws, size_t ws_size,
                              hipStream_t stream) {
    const float* x  = (const float*)d_in[0];
    float* out      = (float*)d_out;
    window_crop_kernel<<<B_TOTAL, BLOCK, 0, stream>>>(x, out);
}

// Round 3
// 41.256 us; speedup vs baseline: 1.2145x; 1.2145x over previous
//
#include <hip/hip_runtime.h>

// Window_Crop: per-batch sliding-window average pooling over 5 aspect ratios
// (stride 1) + argmax over first 4 ratio groups.
//
// Ratios (exact Python float semantics: 1024 // 25.6 == 39.0):
//   (32,32) N=6561  off 0
//   (25,39) N=6512  off 6561
//   (39,25) N=6512  off 13073
//   (38,26) N=6525  off 19585
//   (26,38) N=6525  off 26110   (excluded from argmax)
//   total 32635
//
// One block (512 threads) per image. 113x113 fp32 integral image in LDS
// (51 KB -> 3 blocks/CU, 24 waves/CU). Segmented prefix sums (4 segs x 28,
// register-resident partials + shfl fixup). Each thread emits 2 adjacent
// windows per iteration so all 8 LDS reads share one base register with
// compile-time offsets (ds_read2-fusable).

#define B_TOTAL 1024
#define HW      112
#define NPIX    (HW * HW)
#define PITCH   113
#define TOTAL_W 32635
#define BLOCK   512
#define NSEG    4
#define SEG     28          // 112 / 4

template<int KH, int KW, int OFF, bool TRACK>
__device__ __forceinline__ void windows_group(const float* __restrict__ S,
                                              float* __restrict__ out_scores,
                                              int tid, float& bestv, int& besti) {
    constexpr int OH  = HW - KH + 1;
    constexpr int OW  = HW - KW + 1;
    constexpr int OWP = (OW + 1) / 2;     // column pairs per row
    constexpr int NP  = OH * OWP;
    constexpr int D   = KH * PITCH;       // bottom-row offset (dwords)
    constexpr float inv = 1.0f / (float)(KH * KW);
    for (int p = tid; p < NP; p += BLOCK) {
        const int i  = p / OWP;           // const divisor -> magic mul
        const int j  = (p - i * OWP) * 2;
        const int A  = i * PITCH + j;     // top-left corner
        const int Ab = A + D;             // bottom-left corner
        // 8 reads, two compile-time-offset groups of 4 -> ds_read2_b32 pairs
        const float t0  = S[A],       t1  = S[A + 1];
        const float tK0 = S[A + KW],  tK1 = S[A + KW + 1];
        const float b0  = S[Ab],      b1  = S[Ab + 1];
        const float bK0 = S[Ab + KW], bK1 = S[Ab + KW + 1];
        const int w = i * OW + j;
        const float sc0 = (bK0 - tK0 - b0 + t0) * inv;
        out_scores[OFF + w] = sc0;
        if (TRACK && sc0 > bestv) { bestv = sc0; besti = OFF + w; }
        if ((OW & 1) == 0 || j + 1 < OW) {       // folds away for even OW
            const float sc1 = (bK1 - tK1 - b1 + t1) * inv;
            out_scores[OFF + w + 1] = sc1;
            if (TRACK && sc1 > bestv) { bestv = sc1; besti = OFF + w + 1; }
        }
    }
}

__global__ __launch_bounds__(BLOCK)
void window_crop_kernel(const float* __restrict__ x, float* __restrict__ out) {
    __shared__ float S[PITCH * PITCH];           // 51,076 B integral image
    __shared__ float wv[BLOCK / 64];
    __shared__ int   wi[BLOCK / 64];

    const int b   = blockIdx.x;
    const int tid = threadIdx.x;
    const float* img = x + (size_t)b * NPIX;

    // zero row 0 / col 0
    for (int i = tid; i < PITCH; i += BLOCK) {
        S[i] = 0.0f;
        S[i * PITCH] = 0.0f;
    }

    // load image into S[1..112][1..112] (float4 loads; 112 % 4 == 0)
    const float4* img4 = (const float4*)img;
    for (int i = tid; i < NPIX / 4; i += BLOCK) {
        const int r = i / (HW / 4);
        const int c = (i - r * (HW / 4)) * 4;
        const float4 v = img4[i];
        float* dst = &S[(r + 1) * PITCH + (c + 1)];
        dst[0] = v.x; dst[1] = v.y; dst[2] = v.z; dst[3] = v.w;
    }
    __syncthreads();

    const int lane = tid & 63;
    const int bl   = lane & ~3;       // lane of segment 0 of this line

    // row-wise prefix sums: 112 rows x 4 segments of 28. Partials live in
    // registers (static indices), shfl brings in the preceding segment sums.
    if (tid < HW * NSEG) {
        const int r  = tid >> 2;
        const int s  = tid & 3;
        float* row = &S[(r + 1) * PITCH];
        const int c0 = 1 + s * SEG;
        float pref[SEG];
        float run = 0.0f;
        #pragma unroll
        for (int k = 0; k < SEG; ++k) { run += row[c0 + k]; pref[k] = run; }
        const float v0 = __shfl(run, bl,     64);
        const float v1 = __shfl(run, bl + 1, 64);
        const float v2 = __shfl(run, bl + 2, 64);
        float off = 0.0f;
        if (s > 0) off += v0;
        if (s > 1) off += v1;
        if (s > 2) off += v2;
        #pragma unroll
        for (int k = 0; k < SEG; ++k) row[c0 + k] = pref[k] + off;
    }
    __syncthreads();

    // column-wise prefix sums, same scheme
    if (tid < HW * NSEG) {
        const int c  = tid >> 2;
        const int s  = tid & 3;
        float* col = &S[c + 1];
        const int r0 = 1 + s * SEG;
        float pref[SEG];
        float run = 0.0f;
        #pragma unroll
        for (int k = 0; k < SEG; ++k) { run += col[(r0 + k) * PITCH]; pref[k] = run; }
        const float v0 = __shfl(run, bl,     64);
        const float v1 = __shfl(run, bl + 1, 64);
        const float v2 = __shfl(run, bl + 2, 64);
        float off = 0.0f;
        if (s > 0) off += v0;
        if (s > 1) off += v1;
        if (s > 2) off += v2;
        #pragma unroll
        for (int k = 0; k < SEG; ++k) col[(r0 + k) * PITCH] = pref[k] + off;
    }
    __syncthreads();

    // window scores for all 5 groups + argmax over groups 0..3
    float bestv = -3.402823466e+38f;
    int   besti = 0;
    float* out_scores = out + 2 * B_TOTAL + (size_t)b * TOTAL_W;

    windows_group<32, 32,     0, true >(S, out_scores, tid, bestv, besti);
    windows_group<25, 39,  6561, true >(S, out_scores, tid, bestv, besti);
    windows_group<39, 25, 13073, true >(S, out_scores, tid, bestv, besti);
    windows_group<38, 26, 19585, true >(S, out_scores, tid, bestv, besti);
    windows_group<26, 38, 26110, false>(S, out_scores, tid, bestv, besti);

    // wave-level argmax (first-index tie-break), then 8 partials via LDS
    #pragma unroll
    for (int d = 32; d > 0; d >>= 1) {
        const float ov = __shfl_down(bestv, d, 64);
        const int   oi = __shfl_down(besti, d, 64);
        if (ov > bestv || (ov == bestv && oi < besti)) { bestv = ov; besti = oi; }
    }
    if (lane == 0) { wv[tid >> 6] = bestv; wi[tid >> 6] = besti; }
    __syncthreads();
    if (tid == 0) {
        float bv = wv[0]; int bi = wi[0];
        #pragma unroll
        for (int k = 1; k < BLOCK / 64; ++k) {
            if (wv[k] > bv || (wv[k] == bv && wi[k] < bi)) { bv = wv[k]; bi = wi[k]; }
        }
        out[b]           = (float)bi;    // idx (exact in fp32: < 2^24)
        out[B_TOTAL + b] = bv;           // prop_scores
    }
}

extern "C" void kernel_launch(void* const* d_in, const int* in_sizes, int n_in,
                              void* d_out, int out_size, void* d_ws, size_t ws_size,
                              hipStream_t stream) {
    const float* x = (const float*)d_in[0];
    float* out     = (float*)d_out;
    window_crop_kernel<<<B_TOTAL, BLOCK, 0, stream>>>(x, out);
}